// Round 8
// baseline (36.793 us; speedup 1.0000x reference)
//
#include <hip/hip_runtime.h>

#define NF 64
#define LEN 299592
#define V0 37448            // voxel region start in octree
#define MEAN3_OFF 7607      // 4096 + 3511
#define EPSF 1e-5f

typedef float f32x4 __attribute__((ext_vector_type(4)));

// Single fused kernel. One thread per (f, j) level-4 node, j in [0,32768).
// The level-0..3 prune cascade collapses to a closed form over raw inputs for
// the only consumed m3 bits (i3 in [3511,4096)):
//   m1_61 = lt(125)|lt(70)|lt(15)|lt(8)
//   m2[qq] = lt(512+qq) | lt(qq<488 ? 563 : 564) | m1_61      (qq in [484,494))
//   B[pb]  = lt(4096+pb) | m2[(3512+pb)>>3]                   (pb in [365,439))
//   m3[i3] = lt(4096+i3) | B[(i3-584)>>3]
// Level-4: m4[j] = lt(in[32768+j]) | (j>=4680: lt(in[32768+q]), q=(j-4680)>>3)
//                | m3[i3], i3=(28088+q4)>>3, q4 = j<4680 ? j : q.
// j <  3511: per-child masks lt(child)|m4[j]; write mean4 only.
// j >= 3511: shared m4[j]; write mean4 and pruned children (positions >= 65536).
// Fused: mean3 tail via 8-lane shfl reduce; zero-fill of [0,7607) and [8192,32768).
// NT hints: child loads for j>=3511 are read-once (bypass cache); all stores are
// write-once (never re-read in-kernel) -> nontemporal.
__global__ __launch_bounds__(256) void k_fused(const float* __restrict__ in,
                                               float* __restrict__ out) {
    // XCD swizzle: 8192 blocks, keep each feature's 128 blocks on one XCD
    int b = blockIdx.x;
    int chunk = (b & 7) * 1024 + (b >> 3);
    int f = chunk >> 7;                        // block-uniform (SGPR)
    int j = ((chunk & 127) << 8) + threadIdx.x;
    size_t base = (size_t)f * LEN;
    const float* src = in + base;

    // closed-form m3 bit (head-region reads: L2-resident, mostly wave-broadcast)
    int q4 = (j < 4680) ? j : ((j - 4680) >> 3);
    int i3 = (28088 + q4) >> 3;            // [3511, 4096)
    int pb = (i3 - 584) >> 3;              // [365, 439)
    int qq = (3512 + pb) >> 3;             // [484, 494)
    bool m1_61 = (src[125] < EPSF) || (src[70] < EPSF) ||
                 (src[15] < EPSF) || (src[8] < EPSF);
    bool m2s = (src[(qq < 488) ? 563 : 564] < EPSF) || m1_61;
    bool M2 = (src[512 + qq] < EPSF) || m2s;
    bool Bv = (src[4096 + pb] < EPSF) || M2;
    bool m3b = (src[4096 + i3] < EPSF) || Bv;

    const f32x4* s = (const f32x4*)(src + V0 + 8 * (size_t)j);
    float own = src[32768 + j];
    float mean;
    if (j < 3511) {
        f32x4 a = s[0], c = s[1];              // overlap region: keep cached
        bool mj = (own < EPSF) || m3b;
        if (mj) {
            mean = 0.f;
        } else {
            mean = ((a.x < EPSF ? 0.f : a.x) + (a.y < EPSF ? 0.f : a.y) +
                    (a.z < EPSF ? 0.f : a.z) + (a.w < EPSF ? 0.f : a.w) +
                    (c.x < EPSF ? 0.f : c.x) + (c.y < EPSF ? 0.f : c.y) +
                    (c.z < EPSF ? 0.f : c.z) + (c.w < EPSF ? 0.f : c.w)) * 0.125f;
        }
        __builtin_nontemporal_store(mean, &out[base + 32768 + j]);
    } else {
        f32x4 a = __builtin_nontemporal_load(s);       // read-once region
        f32x4 c = __builtin_nontemporal_load(s + 1);
        bool m;
        if (j < 4680) {
            m = (own < EPSF) || m3b;
        } else {
            m = (own < EPSF) || (src[32768 + q4] < EPSF) || m3b;
        }
        if (m) {
            a = (f32x4)0.f;
            c = (f32x4)0.f;
            mean = 0.f;
        } else {
            mean = (a.x + a.y + a.z + a.w + c.x + c.y + c.z + c.w) * 0.125f;
        }
        __builtin_nontemporal_store(mean, &out[base + 32768 + j]);
        f32x4* d = (f32x4*)(out + base + V0 + 8 * (size_t)j);
        __builtin_nontemporal_store(a, d);
        __builtin_nontemporal_store(c, d + 1);
    }
    // fused mean3 tail (j in [0,4680), groups of 8 within one wave)
    float v = mean;
    v += __shfl_xor(v, 1);
    v += __shfl_xor(v, 2);
    v += __shfl_xor(v, 4);
    if (j < 4680 && (j & 7) == 0)
        __builtin_nontemporal_store(v * 0.125f, &out[base + MEAN3_OFF + (j >> 3)]);
    // fused zero-fill: regions [0,7607) and [8192,32768)
    if (j < 7607 || j >= 8192)
        __builtin_nontemporal_store(0.f, &out[base + j]);
}

extern "C" void kernel_launch(void* const* d_in, const int* in_sizes, int n_in,
                              void* d_out, int out_size, void* d_ws, size_t ws_size,
                              hipStream_t stream) {
    const float* in = (const float*)d_in[0];
    float* out = (float*)d_out;
    k_fused<<<(NF * 32768) / 256, 256, 0, stream>>>(in, out);
}

// Round 9
// 25.226 us; speedup vs baseline: 1.4585x; 1.4585x over previous
//
#include <hip/hip_runtime.h>

#define NF 64
#define LEN 299592
#define V0 37448            // voxel region start in octree
#define MEAN3_OFF 7607      // 4096 + 3511
#define EPSF 1e-5f

// Single fused kernel. One thread per (f, j) level-4 node, j in [0,32768).
// The level-0..3 prune cascade collapses to a closed form over raw inputs for
// the only consumed m3 bits (i3 in [3511,4096)):
//   m1_61 = lt(125)|lt(70)|lt(15)|lt(8)
//   m2[qq] = lt(512+qq) | lt(qq<488 ? 563 : 564) | m1_61      (qq in [484,494))
//   B[pb]  = lt(4096+pb) | m2[(3512+pb)>>3]                   (pb in [365,439))
//   m3[i3] = lt(4096+i3) | B[(i3-584)>>3]
// Level-4: m4[j] = lt(in[32768+j]) | (j>=4680: lt(in[32768+q]), q=(j-4680)>>3)
//                | m3[i3], i3=(28088+q4)>>3, q4 = j<4680 ? j : q.
// j <  3511: per-child masks lt(child)|m4[j]; write mean4 only.
// j >= 3511: shared m4[j]; write mean4 and pruned children (positions >= 65536).
// Fused: mean3 tail via 8-lane shfl reduce; zero-fill of [0,7607) and [8192,32768).
// NOTE (R7 post-mortem): nontemporal load/store hints cost +10 us here — plain
// accesses use the fast write path and L2 covers all reuse. Keep them plain.
__global__ __launch_bounds__(256) void k_fused(const float* __restrict__ in,
                                               float* __restrict__ out) {
    // XCD swizzle: 8192 blocks, keep each feature's 128 blocks on one XCD
    int b = blockIdx.x;
    int chunk = (b & 7) * 1024 + (b >> 3);
    int f = chunk >> 7;                        // block-uniform (SGPR)
    int j = ((chunk & 127) << 8) + threadIdx.x;
    size_t base = (size_t)f * LEN;
    const float* src = in + base;

    // closed-form m3 bit (head-region reads: L2-resident, mostly wave-broadcast)
    int q4 = (j < 4680) ? j : ((j - 4680) >> 3);
    int i3 = (28088 + q4) >> 3;            // [3511, 4096)
    int pb = (i3 - 584) >> 3;              // [365, 439)
    int qq = (3512 + pb) >> 3;             // [484, 494)
    bool m1_61 = (src[125] < EPSF) || (src[70] < EPSF) ||
                 (src[15] < EPSF) || (src[8] < EPSF);
    bool m2s = (src[(qq < 488) ? 563 : 564] < EPSF) || m1_61;
    bool M2 = (src[512 + qq] < EPSF) || m2s;
    bool Bv = (src[4096 + pb] < EPSF) || M2;
    bool m3b = (src[4096 + i3] < EPSF) || Bv;

    const float4* s = (const float4*)(src + V0 + 8 * (size_t)j);
    float own = src[32768 + j];
    float mean;
    if (j < 3511) {
        float4 a = s[0], c = s[1];
        bool mj = (own < EPSF) || m3b;
        if (mj) {
            mean = 0.f;
        } else {
            mean = ((a.x < EPSF ? 0.f : a.x) + (a.y < EPSF ? 0.f : a.y) +
                    (a.z < EPSF ? 0.f : a.z) + (a.w < EPSF ? 0.f : a.w) +
                    (c.x < EPSF ? 0.f : c.x) + (c.y < EPSF ? 0.f : c.y) +
                    (c.z < EPSF ? 0.f : c.z) + (c.w < EPSF ? 0.f : c.w)) * 0.125f;
        }
        out[base + 32768 + j] = mean;
    } else {
        float4 a = s[0], c = s[1];
        bool m;
        if (j < 4680) {
            m = (own < EPSF) || m3b;
        } else {
            m = (own < EPSF) || (src[32768 + q4] < EPSF) || m3b;
        }
        if (m) {
            a = make_float4(0.f, 0.f, 0.f, 0.f);
            c = a;
            mean = 0.f;
        } else {
            mean = (a.x + a.y + a.z + a.w + c.x + c.y + c.z + c.w) * 0.125f;
        }
        out[base + 32768 + j] = mean;
        float4* d = (float4*)(out + base + V0 + 8 * (size_t)j);
        d[0] = a;
        d[1] = c;
    }
    // fused mean3 tail (j in [0,4680), groups of 8 within one wave)
    float v = mean;
    v += __shfl_xor(v, 1);
    v += __shfl_xor(v, 2);
    v += __shfl_xor(v, 4);
    if (j < 4680 && (j & 7) == 0)
        out[base + MEAN3_OFF + (j >> 3)] = v * 0.125f;
    // fused zero-fill: regions [0,7607) and [8192,32768)
    if (j < 7607 || j >= 8192)
        out[base + j] = 0.f;
}

extern "C" void kernel_launch(void* const* d_in, const int* in_sizes, int n_in,
                              void* d_out, int out_size, void* d_ws, size_t ws_size,
                              hipStream_t stream) {
    const float* in = (const float*)d_in[0];
    float* out = (float*)d_out;
    k_fused<<<(NF * 32768) / 256, 256, 0, stream>>>(in, out);
}